// Round 4
// baseline (289.836 us; speedup 1.0000x reference)
//
#include <hip/hip_runtime.h>

#define B_   2
#define NC_  256
#define CN_  256
#define K_   16
#define DN_  64
#define G_   8
#define HM_  128
#define F3_  192

typedef unsigned short u16;
typedef short v8s __attribute__((ext_vector_type(8)));
typedef float v4f __attribute__((ext_vector_type(4)));

// Static LDS (per 128-row block), 53,248 B total -> 2-3 blocks/CU:
//   big [128][132] bf16 = 33,792  (mh then sh; C->A layout round-trip)
//   am  [128][68]  bf16 = 17,408  (agg then msg)
//   hsum/msum [4][64] f32 = 2,048 (per-wave pooled partials)
//
// d_ws: bf16 weights @0 (1 MB): mw1b[196608] mw2b[+196608] sw1b[+262144] sw2b[+458752]
//       parts f32 @ 1 MB: [512][2][128]  (per half-block pooled partial sums)

__device__ __forceinline__ u16 f2b(float f) {
    unsigned v; __builtin_memcpy(&v, &f, 4);
    v = v + 0x7fffu + ((v >> 16) & 1u);   // RNE
    return (u16)(v >> 16);
}
__device__ __forceinline__ v8s cvt8(const float* p) {
    float4 a = *(const float4*)p, b = *(const float4*)(p + 4);
    v8s r;
    r[0] = (short)f2b(a.x); r[1] = (short)f2b(a.y); r[2] = (short)f2b(a.z); r[3] = (short)f2b(a.w);
    r[4] = (short)f2b(b.x); r[5] = (short)f2b(b.y); r[6] = (short)f2b(b.z); r[7] = (short)f2b(b.w);
    return r;
}
__device__ __forceinline__ float gelu_t(float x) {
    // jax.nn.gelu approximate=True: x*sigmoid(2*k0*x*(1+k1*x^2))
    float u = x * x;
    float t = 1.5957691216057308f * x * __builtin_fmaf(0.044715f, u, 1.0f);
    float e = __expf(-t);
    return x * __builtin_amdgcn_rcpf(1.0f + e);
}

__global__ __launch_bounds__(256) void cvt_w(
    const float* __restrict__ mw1, const float* __restrict__ mw2,
    const float* __restrict__ sw1, const float* __restrict__ sw2,
    u16* __restrict__ dst)
{
    int e = (blockIdx.x * 256 + threadIdx.x) * 4;   // 131072 threads * 4 = 524288
    const float* s; int off;
    if      (e < 196608) { s = mw1; off = e; }
    else if (e < 262144) { s = mw2; off = e - 196608; }
    else if (e < 458752) { s = sw1; off = e - 262144; }
    else                 { s = sw2; off = e - 458752; }
    float4 v = *(const float4*)(s + off);
    ushort4 o4;
    o4.x = f2b(v.x); o4.y = f2b(v.y); o4.z = f2b(v.z); o4.w = f2b(v.w);
    *(ushort4*)(dst + e) = o4;
}

__global__ __launch_bounds__(256, 2) void mg_main(
    const float* __restrict__ h,    const float* __restrict__ wconn,
    const float* __restrict__ ctx,  const float* __restrict__ nid,
    const u16* __restrict__ mw1b,   const float* __restrict__ mb1,
    const u16* __restrict__ mw2b,   const float* __restrict__ mb2,
    const u16* __restrict__ sw1b,   const float* __restrict__ sb1,
    const u16* __restrict__ sw2b,   const float* __restrict__ sb2,
    const int* __restrict__ conn,   const int* __restrict__ c2g,
    float* __restrict__ outf,       float* __restrict__ parts)
{
    const int bid  = blockIdx.x;          // 1024 blocks
    const int bn   = bid >> 1;            // (b,cell)
    const int rh   = bid & 1;             // row half: rows [rh*128, rh*128+128)
    const int n    = bn & 255;
    const int tid  = threadIdx.x;
    const int wave = tid >> 6;
    const int lane = tid & 63;
    const int q    = lane >> 4;
    const int ln   = lane & 15;
    const int g    = c2g[n];

    __shared__ u16   big[128 * 132];
    __shared__ u16   am [128 * 68];
    __shared__ float hsumS[4 * 64];
    __shared__ float msumS[4 * 64];

    const size_t hbase = (size_t)bn * (CN_ * DN_);
    const size_t nbase = (size_t)n  * (CN_ * DN_);
    float* oH = outf + (size_t)bn * 16384;
    float* oM = outf + (size_t)8388608 + (size_t)bn * 16384;

    // ---------------- gather (f32 VALU): agg = sum_k w * h[idx] --------------
    // thread t: local row c = t>>1 (wave-private: wave w owns rows [32w,32w+32)),
    // d-half = (t&1)*32. All reads L2-hot.
    {
        const int c    = tid >> 1;
        const int gr   = rh * 128 + c;
        const int d0   = (tid & 1) * 32;
        const int*   cp = conn  + n * 4096 + gr * 16;
        const float* wp = wconn + (size_t)bn * 4096 + gr * 16;
        int   ivv[16]; float wvv[16];
#pragma unroll
        for (int k = 0; k < 16; ++k) { ivv[k] = cp[k]; wvv[k] = wp[k]; }
        float agg[32];
#pragma unroll
        for (int j = 0; j < 32; ++j) agg[j] = 0.0f;
#pragma unroll 4
        for (int k = 0; k < 16; ++k) {
            const float* hp = h + hbase + (size_t)ivv[k] * 64 + d0;
            float w = wvv[k];
#pragma unroll
            for (int jj = 0; jj < 8; ++jj) {
                float4 x = *(const float4*)(hp + jj * 4);
                agg[jj * 4 + 0] = __builtin_fmaf(w, x.x, agg[jj * 4 + 0]);
                agg[jj * 4 + 1] = __builtin_fmaf(w, x.y, agg[jj * 4 + 1]);
                agg[jj * 4 + 2] = __builtin_fmaf(w, x.z, agg[jj * 4 + 2]);
                agg[jj * 4 + 3] = __builtin_fmaf(w, x.w, agg[jj * 4 + 3]);
            }
        }
        u16* dst = am + c * 68 + d0;
#pragma unroll
        for (int j = 0; j < 32; ++j) dst[j] = f2b(agg[j]);
    }
    // no barrier: rows are wave-private from here to the pooled reduce

    const int cbase = wave * 32;   // local rows owned by this wave

    // ---------------- m1: mh = gelu([h|agg|nid] @ mw1^T + mb1) ---------------
    {
        v8s afr[2][6];
#pragma unroll
        for (int mi = 0; mi < 2; ++mi) {
            int c  = cbase + mi * 16 + ln;
            int gc = rh * 128 + c;
            afr[mi][0] = cvt8(h + hbase + (size_t)gc * 64 +  0 + q * 8);
            afr[mi][1] = cvt8(h + hbase + (size_t)gc * 64 + 32 + q * 8);
            afr[mi][2] = *(const v8s*)(am + c * 68 +  0 + q * 8);
            afr[mi][3] = *(const v8s*)(am + c * 68 + 32 + q * 8);
            afr[mi][4] = cvt8(nid + nbase + (size_t)gc * 64 +  0 + q * 8);
            afr[mi][5] = cvt8(nid + nbase + (size_t)gc * 64 + 32 + q * 8);
        }
        const u16* w1g = mw1b + (size_t)g * HM_ * F3_;
#pragma unroll
        for (int nt = 0; nt < 8; ++nt) {
            float b1v = mb1[g * HM_ + nt * 16 + ln];
            v4f acc[2] = {{0,0,0,0},{0,0,0,0}};
#pragma unroll
            for (int ks = 0; ks < 6; ++ks) {
                v8s bf = *(const v8s*)(w1g + (nt * 16 + ln) * F3_ + ks * 32 + q * 8);
#pragma unroll
                for (int mi = 0; mi < 2; ++mi)
                    acc[mi] = __builtin_amdgcn_mfma_f32_16x16x32_bf16(afr[mi][ks], bf, acc[mi], 0, 0, 0);
            }
#pragma unroll
            for (int mi = 0; mi < 2; ++mi) {
                int c = cbase + mi * 16 + q * 4;
#pragma unroll
                for (int r = 0; r < 4; ++r)
                    big[(c + r) * 132 + nt * 16 + ln] = f2b(gelu_t(acc[mi][r] + b1v));
            }
        }
    }

    // ---------------- m2: msg = mh @ mw2^T + mb2 (am + global f32) -----------
    {
        v8s afr[2][4];
#pragma unroll
        for (int mi = 0; mi < 2; ++mi) {
            int c = cbase + mi * 16 + ln;
#pragma unroll
            for (int ks = 0; ks < 4; ++ks)
                afr[mi][ks] = *(const v8s*)(big + c * 132 + ks * 32 + q * 8);
        }
        const u16* w2g = mw2b + (size_t)g * DN_ * HM_;
#pragma unroll
        for (int nt = 0; nt < 4; ++nt) {
            float bb = mb2[g * DN_ + nt * 16 + ln];
            v4f acc[2] = {{0,0,0,0},{0,0,0,0}};
#pragma unroll
            for (int ks = 0; ks < 4; ++ks) {
                v8s bf = *(const v8s*)(w2g + (nt * 16 + ln) * HM_ + ks * 32 + q * 8);
#pragma unroll
                for (int mi = 0; mi < 2; ++mi)
                    acc[mi] = __builtin_amdgcn_mfma_f32_16x16x32_bf16(afr[mi][ks], bf, acc[mi], 0, 0, 0);
            }
            float ms = 0.0f;
            int d = nt * 16 + ln;
#pragma unroll
            for (int mi = 0; mi < 2; ++mi) {
                int c = cbase + mi * 16 + q * 4;
#pragma unroll
                for (int r = 0; r < 4; ++r) {
                    float mv = acc[mi][r] + bb;
                    am[(c + r) * 68 + d] = f2b(mv);
                    oM[(size_t)(rh * 128 + c + r) * 64 + d] = mv;
                    ms += mv;
                }
            }
            // reduce over quads -> per-wave column sums
            ms += __shfl_xor(ms, 16);
            ms += __shfl_xor(ms, 32);
            if (q == 0) msumS[wave * 64 + d] = ms;
        }
    }

    // ---------------- s1: sh = gelu([h|msg|ctx] @ sw1^T + sb1) ---------------
    {
        v8s cfr0 = cvt8(ctx + (size_t)bn * DN_ +  0 + q * 8);
        v8s cfr1 = cvt8(ctx + (size_t)bn * DN_ + 32 + q * 8);
        v8s afr[2][4];
#pragma unroll
        for (int mi = 0; mi < 2; ++mi) {
            int c  = cbase + mi * 16 + ln;
            int gc = rh * 128 + c;
            afr[mi][0] = cvt8(h + hbase + (size_t)gc * 64 +  0 + q * 8);
            afr[mi][1] = cvt8(h + hbase + (size_t)gc * 64 + 32 + q * 8);
            afr[mi][2] = *(const v8s*)(am + c * 68 +  0 + q * 8);
            afr[mi][3] = *(const v8s*)(am + c * 68 + 32 + q * 8);
        }
        const u16* w1g = sw1b + (size_t)g * HM_ * F3_;
#pragma unroll
        for (int nt = 0; nt < 8; ++nt) {
            float b1v = sb1[g * HM_ + nt * 16 + ln];
            v4f acc[2] = {{0,0,0,0},{0,0,0,0}};
#pragma unroll
            for (int ks = 0; ks < 4; ++ks) {
                v8s bf = *(const v8s*)(w1g + (nt * 16 + ln) * F3_ + ks * 32 + q * 8);
#pragma unroll
                for (int mi = 0; mi < 2; ++mi)
                    acc[mi] = __builtin_amdgcn_mfma_f32_16x16x32_bf16(afr[mi][ks], bf, acc[mi], 0, 0, 0);
            }
#pragma unroll
            for (int ks = 4; ks < 6; ++ks) {
                v8s bf = *(const v8s*)(w1g + (nt * 16 + ln) * F3_ + ks * 32 + q * 8);
                v8s aa = (ks == 4) ? cfr0 : cfr1;   // ctx broadcast across rows
#pragma unroll
                for (int mi = 0; mi < 2; ++mi)
                    acc[mi] = __builtin_amdgcn_mfma_f32_16x16x32_bf16(aa, bf, acc[mi], 0, 0, 0);
            }
#pragma unroll
            for (int mi = 0; mi < 2; ++mi) {
                int c = cbase + mi * 16 + q * 4;
#pragma unroll
                for (int r = 0; r < 4; ++r)
                    big[(c + r) * 132 + nt * 16 + ln] = f2b(gelu_t(acc[mi][r] + b1v));
            }
        }
    }

    // ---------------- s2: h_new = h(f32) + sh @ sw2^T + sb2 ------------------
    {
        v8s afr[2][4];
#pragma unroll
        for (int mi = 0; mi < 2; ++mi) {
            int c = cbase + mi * 16 + ln;
#pragma unroll
            for (int ks = 0; ks < 4; ++ks)
                afr[mi][ks] = *(const v8s*)(big + c * 132 + ks * 32 + q * 8);
        }
        const u16* w2g = sw2b + (size_t)g * DN_ * HM_;
#pragma unroll
        for (int nt = 0; nt < 4; ++nt) {
            float bb = sb2[g * DN_ + nt * 16 + ln];
            v4f acc[2] = {{0,0,0,0},{0,0,0,0}};
#pragma unroll
            for (int ks = 0; ks < 4; ++ks) {
                v8s bf = *(const v8s*)(w2g + (nt * 16 + ln) * HM_ + ks * 32 + q * 8);
#pragma unroll
                for (int mi = 0; mi < 2; ++mi)
                    acc[mi] = __builtin_amdgcn_mfma_f32_16x16x32_bf16(afr[mi][ks], bf, acc[mi], 0, 0, 0);
            }
            float hs = 0.0f;
            int d = nt * 16 + ln;
#pragma unroll
            for (int mi = 0; mi < 2; ++mi) {
                int c = cbase + mi * 16 + q * 4;
#pragma unroll
                for (int r = 0; r < 4; ++r) {
                    int gc = rh * 128 + c + r;
                    float hv = h[hbase + (size_t)gc * 64 + d];   // f32 residual
                    float hn = hv + acc[mi][r] + bb;
                    oH[(size_t)gc * 64 + d] = hn;
                    hs += hn;
                }
            }
            hs += __shfl_xor(hs, 16);
            hs += __shfl_xor(hs, 32);
            if (q == 0) hsumS[wave * 64 + d] = hs;
        }
    }
    __syncthreads();

    // ---------------- pooled partial sums (over this block's 128 rows) -------
    if (tid < 128) {
        int col = tid & 63;
        const float* src = (tid < 64) ? hsumS : msumS;
        float s = src[0 * 64 + col] + src[1 * 64 + col] + src[2 * 64 + col] + src[3 * 64 + col];
        parts[(size_t)bn * 256 + rh * 128 + (tid < 64 ? col : 64 + col)] = s;
    }
}

// ---------------- modulation MLP (f32): mod = gelu(p@w1+b1)@w2+b2 ------------
__global__ __launch_bounds__(128) void mg_mod(
    const float* __restrict__ w1, const float* __restrict__ b1,
    const float* __restrict__ w2, const float* __restrict__ b2,
    const float* __restrict__ parts, float* __restrict__ outf)
{
    const int bn = blockIdx.x, n = bn & 255, t = threadIdx.x;
    const int col = t & 63, fh = t >> 6;
    const float* pr = parts + (size_t)bn * 256;
    __shared__ float r1[64];

    float acc = (fh == 0) ? b1[n * 64 + col] : 0.0f;
    for (int f = fh * 64; f < fh * 64 + 64; ++f) {
        float pv = (pr[f] + pr[128 + f]) * (1.0f / 256.0f);
        acc = __builtin_fmaf(pv, w1[(n * 128 + f) * 64 + col], acc);
    }
    if (fh == 1) r1[col] = acc;
    __syncthreads();
    if (fh == 0) {
        float ph = gelu_t(acc + r1[col]);
        float part[5];
#pragma unroll
        for (int o = 0; o < 5; ++o) part[o] = ph * w2[(n * 64 + col) * 5 + o];
#pragma unroll
        for (int off = 32; off > 0; off >>= 1)
#pragma unroll
            for (int o = 0; o < 5; ++o) part[o] += __shfl_down(part[o], off);
        if (col == 0) {
#pragma unroll
            for (int o = 0; o < 5; ++o)
                outf[(size_t)16777216 + bn * 5 + o] = part[o] + b2[n * 5 + o];
        }
    }
}

extern "C" void kernel_launch(void* const* d_in, const int* in_sizes, int n_in,
                              void* d_out, int out_size, void* d_ws, size_t ws_size,
                              hipStream_t stream) {
    const float* h     = (const float*)d_in[0];
    const float* wconn = (const float*)d_in[1];
    const float* ctx   = (const float*)d_in[2];
    const float* nid   = (const float*)d_in[3];
    const float* mw1   = (const float*)d_in[4];
    const float* mb1   = (const float*)d_in[5];
    const float* mw2   = (const float*)d_in[6];
    const float* mb2   = (const float*)d_in[7];
    const float* sw1   = (const float*)d_in[8];
    const float* sb1   = (const float*)d_in[9];
    const float* sw2   = (const float*)d_in[10];
    const float* sb2   = (const float*)d_in[11];
    const float* dw1   = (const float*)d_in[12];
    const float* db1   = (const float*)d_in[13];
    const float* dw2   = (const float*)d_in[14];
    const float* db2   = (const float*)d_in[15];
    const int* conn    = (const int*)d_in[16];
    const int* c2g     = (const int*)d_in[17];
    float* outf  = (float*)d_out;
    u16*   wb    = (u16*)d_ws;                        // bf16 weight copies (1 MB)
    float* parts = (float*)((char*)d_ws + 1048576);   // [512][2][128] partial sums

    cvt_w<<<512, 256, 0, stream>>>(mw1, mw2, sw1, sw2, wb);
    mg_main<<<1024, 256, 0, stream>>>(h, wconn, ctx, nid,
                                      wb,           mb1,
                                      wb + 196608,  mb2,
                                      wb + 262144,  sb1,
                                      wb + 458752,  sb2,
                                      conn, c2g, outf, parts);
    mg_mod<<<512, 128, 0, stream>>>(dw1, db1, dw2, db2, parts, outf);
}